// Round 14
// baseline (34.304 us; speedup 1.0000x reference)
//
#include <hip/hip_runtime.h>
#include <math.h>
#include <stdint.h>

// out[b,o] = min_i(W[o,i]+X[b,i]) + max_i(W[o,i]+X[b,i])
// B=1024, OUT=1024, IN=512, fp32.
//
// R14 = R6 geometry (64x32 tile, 256thr/4 waves, wave-private k-slice 128,
// dbuf LDS, 512 blocks = 2/CU) + HAND-SCHEDULED DS pipeline:
//  - every main-loop ds_read/ds_write is inline asm; waits are explicit
//    counted `s_waitcnt lgkmcnt(N)` + sched_barrier(0) (rule #18) so the
//    LDS pipe NEVER drains (R4-R13 all measured wall = LDS + VALU fully
//    serialized; compiler drain-waits are the culprit, cf. T3/T4).
//  - k-paired LDS layout: quad = [a,k0],[a,k1],[a+1,k0],[a+1,k1] ->
//    f2 add (v_pk_add_f32) + v_min3 + v_max3 = 1.5 VALU/triple, and
//    staging is 6 ds_write_b64/thread/stage.
//  - X pair-blocks permuted (q*128 + im*16) -> conflict-free b128 reads.
// Schedule/slot: wait(cur set); sb(0); COMPUTE(cur); issue next set.
// Counts hand-derived (DS completes in-order): 6/6/12/6 per stage.

typedef float f4 __attribute__((ext_vector_type(4)));
typedef float f2 __attribute__((ext_vector_type(2)));

constexpr int B_DIM  = 1024;
constexpr int O_DIM  = 1024;
constexpr int IN_DIM = 512;

constexpr int TM = 64;    // batch-tile
constexpr int TN = 32;    // out-tile
constexpr int KW = 128;   // k per wave (512 / 4 waves)
constexpr int BK = 8;     // k per stage (4 k-pairs)

__global__ __launch_bounds__(256) void tropical_gemm(
    const float* __restrict__ X, const float* __restrict__ W,
    float* __restrict__ out) {
    __shared__ float lds[8192];   // 32 KB: 4 waves x 6 KB loop; merge overlay

    const int tid  = threadIdx.x;
    const int w    = tid >> 6;
    const int lane = tid & 63;
    const int im   = lane >> 3;    // micro-row block 0..7 (8 X rows)
    const int in_  = lane & 7;     // micro-col block 0..7 (4 W cols)
    const int b0   = blockIdx.y * TM;
    const int o0   = blockIdx.x * TN;
    const int wrow = lane >> 1;          // W staging: 2 lanes per o-row
    const int wk4  = (lane & 1) * 4;     // which k-half of the row's 8

    const float* Xp = X + (size_t)(b0 + lane) * IN_DIM + w * KW;
    const float* Wp = W + (size_t)(o0 + wrow) * IN_DIM + w * KW + wk4;

    // LDS u32 byte addresses (low 32 bits of generic LDS pointer = offset).
    // Wave region 6144 B = 2 buffers x 3072 (X 2048 | W 1024).
    // X buffer: kp-row 512 B; pair a at byte ((a&7)>>1)*128 + (a&1)*8 + (a>>3)*16
    //   -> lane's read quad q (rows im*8+2q..+1) at q*128 + im*16 (conflict-free).
    // W buffer: kp-row 256 B; pair b at b*8.
    const uint32_t lbase = (uint32_t)(uintptr_t)lds + w * 6144;
    const uint32_t xr0 = lbase + im * 16;          // X read base, buf0
    const uint32_t xr1 = xr0 + 3072;
    const uint32_t wr0 = lbase + 2048 + in_ * 32;  // W read base, buf0
    const uint32_t wr1 = wr0 + 3072;
    const uint32_t xw0 = lbase + ((lane & 7) >> 1) * 128 + (lane & 1) * 8
                               + (lane >> 3) * 16; // X write base (pair a=lane)
    const uint32_t xw1 = xw0 + 3072;
    const uint32_t ww0 = lbase + 2048 + wk4 * 128 + wrow * 8;
    const uint32_t ww1 = ww0 + 3072;

    float mn[8][4], mx[8][4];
#pragma unroll
    for (int i = 0; i < 8; ++i)
#pragma unroll
        for (int j = 0; j < 4; ++j) { mn[i][j] = INFINITY; mx[i][j] = -INFINITY; }

    // ---- asm primitives ----
#define WAITL(N)                                                              \
    do {                                                                      \
        asm volatile("s_waitcnt lgkmcnt(%c0)" ::"i"(N) : "memory");           \
        __builtin_amdgcn_sched_barrier(0);                                    \
    } while (0)

    // 6 ds_read_b128: X quads q=0..3 (offsets kp*512 + q*128), W quads 0..1
#define RD(P, XB, WB, KP)                                                     \
    do {                                                                      \
        asm volatile("ds_read_b128 %0, %1 offset:%c2"                         \
                     : "=v"(P##x0) : "v"(XB), "i"((KP)*512 + 0));             \
        asm volatile("ds_read_b128 %0, %1 offset:%c2"                         \
                     : "=v"(P##x1) : "v"(XB), "i"((KP)*512 + 128));           \
        asm volatile("ds_read_b128 %0, %1 offset:%c2"                         \
                     : "=v"(P##x2) : "v"(XB), "i"((KP)*512 + 256));           \
        asm volatile("ds_read_b128 %0, %1 offset:%c2"                         \
                     : "=v"(P##x3) : "v"(XB), "i"((KP)*512 + 384));           \
        asm volatile("ds_read_b128 %0, %1 offset:%c2"                         \
                     : "=v"(P##w0) : "v"(WB), "i"((KP)*256 + 0));             \
        asm volatile("ds_read_b128 %0, %1 offset:%c2"                         \
                     : "=v"(P##w1) : "v"(WB), "i"((KP)*256 + 16));            \
    } while (0)

    // 6 ds_write_b64 staging one 8k chunk (4 X pairs + 2 W pairs)
#define WRT(XB, WB)                                                           \
    do {                                                                      \
        f2 t0_ = __builtin_shufflevector(xa, xa, 0, 1);                       \
        f2 t1_ = __builtin_shufflevector(xa, xa, 2, 3);                       \
        f2 t2_ = __builtin_shufflevector(xb, xb, 0, 1);                       \
        f2 t3_ = __builtin_shufflevector(xb, xb, 2, 3);                       \
        f2 t4_ = __builtin_shufflevector(wv, wv, 0, 1);                       \
        f2 t5_ = __builtin_shufflevector(wv, wv, 2, 3);                       \
        asm volatile("ds_write_b64 %0, %1 offset:0"    ::"v"(XB), "v"(t0_) : "memory"); \
        asm volatile("ds_write_b64 %0, %1 offset:512"  ::"v"(XB), "v"(t1_) : "memory"); \
        asm volatile("ds_write_b64 %0, %1 offset:1024" ::"v"(XB), "v"(t2_) : "memory"); \
        asm volatile("ds_write_b64 %0, %1 offset:1536" ::"v"(XB), "v"(t3_) : "memory"); \
        asm volatile("ds_write_b64 %0, %1 offset:0"    ::"v"(WB), "v"(t4_) : "memory"); \
        asm volatile("ds_write_b64 %0, %1 offset:256"  ::"v"(WB), "v"(t5_) : "memory"); \
    } while (0)

#define PF(STG)                                                               \
    do {                                                                      \
        xa = *(const f4*)(Xp + (STG) * BK);                                   \
        xb = *(const f4*)(Xp + (STG) * BK + 4);                               \
        wv = *(const f4*)(Wp + (STG) * BK);                                   \
    } while (0)

    // one x-pair (row, 2k) vs one w-quad (2 cols): 2 pk_add + 2 min3 + 2 max3
#define CW(XP, WQ, R, C0)                                                     \
    do {                                                                      \
        f2 wl_ = __builtin_shufflevector(WQ, WQ, 0, 1);                       \
        f2 wh_ = __builtin_shufflevector(WQ, WQ, 2, 3);                       \
        f2 s0_ = (XP) + wl_;                                                  \
        f2 s1_ = (XP) + wh_;                                                  \
        asm("v_min3_f32 %0, %1, %2, %0"                                       \
            : "+v"(mn[R][C0]) : "v"(s0_[0]), "v"(s0_[1]));                    \
        asm("v_max3_f32 %0, %1, %2, %0"                                       \
            : "+v"(mx[R][C0]) : "v"(s0_[0]), "v"(s0_[1]));                    \
        asm("v_min3_f32 %0, %1, %2, %0"                                       \
            : "+v"(mn[R][(C0) + 1]) : "v"(s1_[0]), "v"(s1_[1]));              \
        asm("v_max3_f32 %0, %1, %2, %0"                                       \
            : "+v"(mx[R][(C0) + 1]) : "v"(s1_[0]), "v"(s1_[1]));              \
    } while (0)

#define CQ(P, XQ, R0)                                                         \
    do {                                                                      \
        f2 xl_ = __builtin_shufflevector(P##XQ, P##XQ, 0, 1);                 \
        f2 xh_ = __builtin_shufflevector(P##XQ, P##XQ, 2, 3);                 \
        CW(xl_, P##w0, (R0), 0);                                              \
        CW(xh_, P##w0, (R0) + 1, 0);                                          \
        CW(xl_, P##w1, (R0), 2);                                              \
        CW(xh_, P##w1, (R0) + 1, 2);                                          \
    } while (0)

#define COMPUTE(P)                                                            \
    do { CQ(P, x0, 0); CQ(P, x1, 2); CQ(P, x2, 4); CQ(P, x3, 6); } while (0)

    // one stage = 4 kp slots; counts derived from in-order DS completion
#define STAGE_BODY(XRC, WRC, XWN, WWN, XRN, WRN, PFS, DOPF, DOW, DONXT)       \
    do {                                                                      \
        WAITL(6);  COMPUTE(A); RD(A, XRC, WRC, 2);   /* slot0 */              \
        WAITL(6);  COMPUTE(B);                        /* slot1 */             \
        if (DOW) WRT(XWN, WWN);                                               \
        if (DOPF) PF(PFS);                                                    \
        RD(B, XRC, WRC, 3);                                                   \
        WAITL((DOW) ? 12 : 6); COMPUTE(A);            /* slot2 */             \
        if (DONXT) RD(A, XRN, WRN, 0);                                        \
        WAITL((DONXT) ? 6 : 0); COMPUTE(B);           /* slot3 */             \
        if (DONXT) RD(B, XRN, WRN, 1);                                        \
    } while (0)

    // rotating fragment sets
    f4 Ax0, Ax1, Ax2, Ax3, Aw0, Aw1;
    f4 Bx0, Bx1, Bx2, Bx3, Bw0, Bw1;
    f4 xa, xb, wv;

    // ---- prologue: stage0 staged, stage1 globals in g, kp0/kp1 in flight ----
    PF(0);
    WRT(xw0, ww0);
    PF(1);
    RD(A, xr0, wr0, 0);
    RD(B, xr0, wr0, 1);

#pragma unroll 1
    for (int s2 = 0; s2 < 7; ++s2) {          // stages 0..13
        STAGE_BODY(xr0, wr0, xw1, ww1, xr1, wr1, 2 * s2 + 2, 1, 1, 1);
        STAGE_BODY(xr1, wr1, xw0, ww0, xr0, wr0, 2 * s2 + 3, 1, 1, 1);
    }
    STAGE_BODY(xr0, wr0, xw1, ww1, xr1, wr1, 0, 0, 1, 1);   // stage 14
    STAGE_BODY(xr1, wr1, xw1, ww1, xr1, wr1, 0, 0, 0, 0);   // stage 15

#undef WAITL
#undef RD
#undef WRT
#undef PF
#undef CW
#undef CQ
#undef COMPUTE
#undef STAGE_BODY

    // ---- merge 4 wave partials: 2-round LDS tree (R6 verbatim) ----
#define DUMP_STATE(slotbase)                                                  \
    do {                                                                      \
        float* p_ = (slotbase) + lane * 4;                                    \
        _Pragma("unroll")                                                     \
        for (int r_ = 0; r_ < 8; ++r_) {                                      \
            *(float4*)(p_ + r_ * 256) =                                       \
                make_float4(mn[r_][0], mn[r_][1], mn[r_][2], mn[r_][3]);      \
            *(float4*)(p_ + (8 + r_) * 256) =                                 \
                make_float4(mx[r_][0], mx[r_][1], mx[r_][2], mx[r_][3]);      \
        }                                                                     \
    } while (0)

#define MERGE_STATE(slotbase)                                                 \
    do {                                                                      \
        const float* p_ = (slotbase) + lane * 4;                              \
        _Pragma("unroll")                                                     \
        for (int r_ = 0; r_ < 8; ++r_) {                                      \
            float4 vn_ = *(const float4*)(p_ + r_ * 256);                     \
            float4 vx_ = *(const float4*)(p_ + (8 + r_) * 256);               \
            mn[r_][0] = fminf(mn[r_][0], vn_.x);                              \
            mn[r_][1] = fminf(mn[r_][1], vn_.y);                              \
            mn[r_][2] = fminf(mn[r_][2], vn_.z);                              \
            mn[r_][3] = fminf(mn[r_][3], vn_.w);                              \
            mx[r_][0] = fmaxf(mx[r_][0], vx_.x);                              \
            mx[r_][1] = fmaxf(mx[r_][1], vx_.y);                              \
            mx[r_][2] = fmaxf(mx[r_][2], vx_.z);                              \
            mx[r_][3] = fmaxf(mx[r_][3], vx_.w);                              \
        }                                                                     \
    } while (0)

    float* slotA = lds;           // 4096 floats
    float* slotB = lds + 4096;

    __syncthreads();
    if (w == 2) DUMP_STATE(slotA);
    if (w == 3) DUMP_STATE(slotB);
    __syncthreads();
    if (w == 0) MERGE_STATE(slotA);   // w0 <- {w0,w2}
    if (w == 1) MERGE_STATE(slotB);   // w1 <- {w1,w3}
    __syncthreads();
    if (w == 1) DUMP_STATE(slotA);
    __syncthreads();
    if (w == 0) {
        MERGE_STATE(slotA);           // w0 <- all
        float* op = out + (size_t)(b0 + im * 8) * O_DIM + o0 + in_ * 4;
#pragma unroll
        for (int r = 0; r < 8; ++r)
            *(float4*)(op + (size_t)r * O_DIM) =
                make_float4(mn[r][0] + mx[r][0], mn[r][1] + mx[r][1],
                            mn[r][2] + mx[r][2], mn[r][3] + mx[r][3]);
    }
#undef DUMP_STATE
#undef MERGE_STATE
}

extern "C" void kernel_launch(void* const* d_in, const int* in_sizes, int n_in,
                              void* d_out, int out_size, void* d_ws, size_t ws_size,
                              hipStream_t stream) {
    (void)in_sizes; (void)n_in; (void)d_ws; (void)ws_size; (void)out_size;
    const float* X = (const float*)d_in[0];
    const float* W = (const float*)d_in[1];
    float* out     = (float*)d_out;

    dim3 grid(O_DIM / TN, B_DIM / TM);  // (32, 16) = 512 blocks = 2/CU
    tropical_gemm<<<grid, dim3(256), 0, stream>>>(X, W, out);
}